// Round 5
// baseline (123.413 us; speedup 1.0000x reference)
//
#include <hip/hip_runtime.h>
#include <hip/hip_fp16.h>

// FixedPointLSTMCell on MI355X — R5: m201-style 8-wave phase-split schedule.
// Tile 256 rows x (64 h-cols x 4 gates = 256 gate-major weight rows), BK=64,
// LDS 128 KB double-buffered, raw s_barrier phases, early-issue prefetch,
// T2 XOR swizzle + T5 setprio. Two sequential K-phases (X·Wi^T then H·Wh^T)
// with phase-0 result rounded to Q8.8 and stashed as packed i16 pairs.
// Exactness: all fake_quant'd operands are integers at scale 2^8; f16 MFMA on
// scaled ints is exact (fp32 accum < 2^24); elementwise replicates reference
// fp32 exactly (rintf = half-even, correctly-rounded /6, exact dyadic scales).

typedef _Float16 half8 __attribute__((ext_vector_type(8)));
typedef float f32x4 __attribute__((ext_vector_type(4)));

#define AS1 __attribute__((address_space(1)))
#define AS3 __attribute__((address_space(3)))

__device__ __forceinline__ void gload16(const void* g, void* l) {
  __builtin_amdgcn_global_load_lds((const AS1 void*)g, (AS3 void*)l, 16, 0, 0);
}

__device__ __forceinline__ float quant256(float v) {
  float q = rintf(v * 256.0f);
  return fminf(fmaxf(q, -32767.0f), 32767.0f);
}

// ---------------- prep: quantize inputs to integer-valued fp16 ----------------
__global__ __launch_bounds__(256) void prep_kernel(
    const float* __restrict__ x, const float* __restrict__ h,
    const float* __restrict__ Wi, const float* __restrict__ Wh,
    const float* __restrict__ bi, const float* __restrict__ bh,
    __half* __restrict__ xq, __half* __restrict__ hq,
    __half* __restrict__ wiq, __half* __restrict__ whq,
    float* __restrict__ biq, float* __restrict__ bhq) {
  const int i = blockIdx.x * 256 + threadIdx.x;  // 4 elems each
  {
    const float4 vx = ((const float4*)x)[i];
    const float4 vh = ((const float4*)h)[i];
    union { __half hh[4]; uint2 u; } ux, uh;
    ux.hh[0] = __half(quant256(vx.x)); ux.hh[1] = __half(quant256(vx.y));
    ux.hh[2] = __half(quant256(vx.z)); ux.hh[3] = __half(quant256(vx.w));
    uh.hh[0] = __half(quant256(vh.x)); uh.hh[1] = __half(quant256(vh.y));
    uh.hh[2] = __half(quant256(vh.z)); uh.hh[3] = __half(quant256(vh.w));
    ((uint2*)xq)[i] = ux.u;
    ((uint2*)hq)[i] = uh.u;
  }
  if (i < 262144) {  // weights: 2048*512/4
    const float4 vi4 = ((const float4*)Wi)[i];
    const float4 vh4 = ((const float4*)Wh)[i];
    union { __half hh[4]; uint2 u; } uwi, uwh;
    uwi.hh[0] = __half(quant256(vi4.x)); uwi.hh[1] = __half(quant256(vi4.y));
    uwi.hh[2] = __half(quant256(vi4.z)); uwi.hh[3] = __half(quant256(vi4.w));
    uwh.hh[0] = __half(quant256(vh4.x)); uwh.hh[1] = __half(quant256(vh4.y));
    uwh.hh[2] = __half(quant256(vh4.z)); uwh.hh[3] = __half(quant256(vh4.w));
    ((uint2*)wiq)[i] = uwi.u;
    ((uint2*)whq)[i] = uwh.u;
  }
  if (i < 512) {  // biases (scaled-int, as float)
    #pragma unroll
    for (int j = 0; j < 4; ++j) {
      biq[i * 4 + j] = quant256(bi[i * 4 + j]);
      bhq[i * 4 + j] = quant256(bh[i * 4 + j]);
    }
  }
}

// ---------------- 8-wave phase-split gate-fused GEMM + LSTM cell ----------------
// 512 threads = 8 waves (wm = wid>>2 in {0,1} row-half; wn = wid&3 col-quarter).
// Per wave: 128 rows (m-frags 0..7) x 64 wrows (n-frags 0..3, n == gate:
// global weight row = n*512 + col0 + wn*16 + l15).
// Per K-tile (BK=64): 4 phases; phase p: mh=p>>1, ks=p&1; 8 ds_read + 16 MFMA.
// Prefetch for tile t+1 issued at phases 0 (A) and 1 (B); drained by vmcnt(0)
// at end of phase 3 (~2.5 phases of latency cover). Each wave stages exactly
// the LDS slabs it reads -> per-wave vmcnt + phase barrier = safe handoff.
__global__ __launch_bounds__(512, 2) void lstm_gemm(
    const __half* __restrict__ xq, const __half* __restrict__ hq,
    const __half* __restrict__ wiq, const __half* __restrict__ whq,
    const float* __restrict__ biq, const float* __restrict__ bhq,
    const float* __restrict__ cprev,
    float* __restrict__ out_h, float* __restrict__ out_c) {
  __shared__ __align__(16) __half sA[2][256 * 64];  // 64 KB
  __shared__ __align__(16) __half sW[2][256 * 64];  // 64 KB

  const int tid = threadIdx.x;
  const int lane = tid & 63;
  const int wid = tid >> 6;      // 0..7
  const int wm = wid >> 2;       // 0..1 : 128-row half
  const int wn = wid & 3;        // 0..3 : 16-col quarter
  const int l15 = lane & 15;
  const int l4 = lane >> 4;
  const int s7 = l15 & 7;                                  // read-swizzle key
  const int gswz = (((lane & 7) ^ ((lane >> 3) & 7)) << 3);  // stage-swizzle

  // XCD-aware swizzle (512 % 8 == 0): XCD x gets 8 consecutive M-tiles x all
  // 8 N-tiles -> weights fully L2-resident per XCD after first M-tile.
  const int bid = blockIdx.x;
  const int lbid = (bid & 7) * 64 + (bid >> 3);
  const int tileM = lbid >> 3;   // 0..63
  const int tileN = lbid & 7;    // 0..7
  const int row0 = tileM * 256;
  const int col0 = tileN * 64;

  const int arow = wm * 128 + l15;   // A fragment base row
  const int brow = wn * 64 + l15;    // B fragment base row (LDS, gate-major)

  f32x4 acc[8][4];
  unsigned int stash[64];

  // stage A-slab[wm]: chunks ca = wm*16 + wn*4 + i (1 KB = 8 rows each)
  #define STAGE_A(dst, kkv)                                                   \
    {                                                                         \
      _Pragma("unroll")                                                       \
      for (int i2 = 0; i2 < 4; ++i2) {                                        \
        const int ca = wm * 16 + wn * 4 + i2;                                 \
        const int r = ca * 8 + (lane >> 3);                                   \
        const int goff = (row0 + r) * 512 + (kkv) + gswz;                     \
        gload16(Ap + goff, (char*)&sA[dst][0] + ca * 1024);                   \
      }                                                                       \
    }
  // stage B-slab[wn] (gate-major rows): chunks cb = wn*8 + wm*4 + i
  #define STAGE_B(dst, kkv)                                                   \
    {                                                                         \
      _Pragma("unroll")                                                       \
      for (int i2 = 0; i2 < 4; ++i2) {                                        \
        const int cb = wn * 8 + wm * 4 + i2;                                  \
        const int r = cb * 8 + (lane >> 3);                                   \
        const int grow = ((r >> 4) & 3) * 512 + col0 + (r >> 6) * 16 + (r & 15); \
        const int goff = grow * 512 + (kkv) + gswz;                           \
        gload16(Wp + goff, (char*)&sW[dst][0] + cb * 1024);                   \
      }                                                                       \
    }

  #define PHASE(cur, tt, p, kkn)                                              \
    {                                                                         \
      const int kb = ((p) & 1) * 4 + l4;                                      \
      const int xo = ((kb ^ s7) << 3);                                        \
      half8 av[4], bv[4];                                                     \
      _Pragma("unroll")                                                       \
      for (int q = 0; q < 4; ++q)                                             \
        av[q] = *(const half8*)&sA[cur][(arow + ((p) >> 1) * 64 + q * 16) * 64 + xo]; \
      _Pragma("unroll")                                                       \
      for (int n = 0; n < 4; ++n)                                             \
        bv[n] = *(const half8*)&sW[cur][(brow + n * 16) * 64 + xo];           \
      if ((tt) < 7) {                                                         \
        if ((p) == 0) STAGE_A((cur) ^ 1, kkn)                                 \
        else if ((p) == 1) STAGE_B((cur) ^ 1, kkn)                            \
      }                                                                       \
      __builtin_amdgcn_s_barrier();                                           \
      asm volatile("s_waitcnt lgkmcnt(0)" ::: "memory");                      \
      __builtin_amdgcn_sched_barrier(0);                                      \
      __builtin_amdgcn_s_setprio(1);                                          \
      _Pragma("unroll")                                                       \
      for (int n = 0; n < 4; ++n)                                             \
        _Pragma("unroll")                                                     \
        for (int q = 0; q < 4; ++q)                                           \
          acc[((p) >> 1) * 4 + q][n] = __builtin_amdgcn_mfma_f32_16x16x32_f16( \
              av[q], bv[n], acc[((p) >> 1) * 4 + q][n], 0, 0, 0);             \
      __builtin_amdgcn_s_setprio(0);                                          \
      if ((p) == 3) asm volatile("s_waitcnt vmcnt(0)" ::: "memory");          \
      __builtin_amdgcn_s_barrier();                                           \
    }

  for (int ph = 0; ph < 2; ++ph) {
    const __half* __restrict__ Ap = ph ? hq : xq;
    const __half* __restrict__ Wp = ph ? whq : wiq;

    // prologue: stage tile 0, then zero acc while loads fly
    STAGE_A(0, 0)
    STAGE_B(0, 0)
    const f32x4 zero = {0.f, 0.f, 0.f, 0.f};
    #pragma unroll
    for (int m = 0; m < 8; ++m)
      #pragma unroll
      for (int n = 0; n < 4; ++n) acc[m][n] = zero;
    asm volatile("s_waitcnt vmcnt(0)" ::: "memory");
    __builtin_amdgcn_s_barrier();

    for (int t = 0; t < 8; t += 2) {
      const int kn1 = (t + 1) * 64;
      const int kn2 = (t + 2) * 64;
      PHASE(0, t, 0, kn1) PHASE(0, t, 1, kn1)
      PHASE(0, t, 2, kn1) PHASE(0, t, 3, kn1)
      PHASE(1, t + 1, 0, kn2) PHASE(1, t + 1, 1, kn2)
      PHASE(1, t + 1, 2, kn2) PHASE(1, t + 1, 3, kn2)
    }

    if (ph == 0) {
      // mini-epilogue: round gi to Q8.8 ints (+bias), pack i16 pairs
      #pragma unroll
      for (int n = 0; n < 4; ++n) {
        const float bvi = biq[n * 512 + col0 + wn * 16 + l15];
        #pragma unroll
        for (int m = 0; m < 8; ++m) {
          #pragma unroll
          for (int jp = 0; jp < 2; ++jp) {
            float g0 = rintf(acc[m][n][jp * 2] * (1.0f / 256.0f) + bvi);
            g0 = fminf(fmaxf(g0, -32767.f), 32767.f);
            float g1 = rintf(acc[m][n][jp * 2 + 1] * (1.0f / 256.0f) + bvi);
            g1 = fminf(fmaxf(g1, -32767.f), 32767.f);
            const int a = (int)g0, b2 = (int)g1;
            stash[(m * 4 + n) * 2 + jp] =
                ((unsigned int)a & 0xffffu) | ((unsigned int)b2 << 16);
          }
        }
      }
    }
  }
  #undef PHASE
  #undef STAGE_A
  #undef STAGE_B

  // ---- final epilogue: s = stash(gi) + round(gh); gates -> c, h ----
  float bvh[4];
  #pragma unroll
  for (int n = 0; n < 4; ++n)
    bvh[n] = bhq[n * 512 + col0 + wn * 16 + l15];

  #pragma unroll
  for (int m = 0; m < 8; ++m)
    #pragma unroll
    for (int j = 0; j < 4; ++j) {
      float s[4];
      #pragma unroll
      for (int g = 0; g < 4; ++g) {
        const unsigned int p = stash[(m * 4 + g) * 2 + (j >> 1)];
        const float gi = (float)((j & 1) ? (short)(p >> 16) : (short)(p & 0xffffu));
        float gh = rintf(acc[m][g][j] * (1.0f / 256.0f) + bvh[g]);
        gh = fminf(fmaxf(gh, -32767.f), 32767.f);
        s[g] = gi + gh;  // pre-activation * 256 (exact int)
      }
      float vi, vf, vo, gg;
      {
        float t0 = (s[0] * (1.0f / 256.0f)) / 6.0f + 0.5f;
        vi = rintf(fminf(fmaxf(t0, 0.0f), 1.0f) * 256.0f);
      }
      {
        float t1 = (s[1] * (1.0f / 256.0f)) / 6.0f + 0.5f;
        vf = rintf(fminf(fmaxf(t1, 0.0f), 1.0f) * 256.0f);
      }
      gg = fminf(fmaxf(s[2], -256.f), 256.f);  // hard_tanh + quant == clip
      {
        float t3 = (s[3] * (1.0f / 256.0f)) / 6.0f + 0.5f;
        vo = rintf(fminf(fmaxf(t3, 0.0f), 1.0f) * 256.0f);
      }
      const int R = row0 + wm * 128 + m * 16 + l4 * 4 + j;
      const int C = col0 + wn * 16 + l15;
      const float cpq = quant256(cprev[R * 512 + C]);
      const float cnum = vf * cpq + vi * gg;       // exact int, scale 2^16
      const float cval = cnum * (1.0f / 65536.0f);
      out_c[R * 512 + C] = cval;
      const float tt2 = fminf(fmaxf(cval, -1.0f), 1.0f);
      const float th = rintf(tt2 * 256.0f);
      out_h[R * 512 + C] = (vo * th) * (1.0f / 65536.0f);
    }
}

extern "C" void kernel_launch(void* const* d_in, const int* in_sizes, int n_in,
                              void* d_out, int out_size, void* d_ws, size_t ws_size,
                              hipStream_t stream) {
  const float* x      = (const float*)d_in[0];
  const float* h_prev = (const float*)d_in[1];
  const float* c_prev = (const float*)d_in[2];
  const float* W_ih   = (const float*)d_in[3];
  const float* b_ih   = (const float*)d_in[4];
  const float* W_hh   = (const float*)d_in[5];
  const float* b_hh   = (const float*)d_in[6];
  float* out = (float*)d_out;

  char* ws = (char*)d_ws;
  __half* xqp  = (__half*)(ws);
  __half* hqp  = (__half*)(ws + (16u << 20));
  __half* wiqp = (__half*)(ws + (32u << 20));
  __half* whqp = (__half*)(ws + (34u << 20));
  float*  biqp = (float*)(ws + (36u << 20));
  float*  bhqp = (float*)(ws + (36u << 20) + 8192);

  prep_kernel<<<8192, 256, 0, stream>>>(x, h_prev, W_ih, W_hh, b_ih, b_hh,
                                        xqp, hqp, wiqp, whqp, biqp, bhqp);

  lstm_gemm<<<512, 512, 0, stream>>>(xqp, hqp, wiqp, whqp, biqp, bhqp,
                                     c_prev, out, out + 8388608);
}